// Round 10
// baseline (4216.142 us; speedup 1.0000x reference)
//
#include <hip/hip_runtime.h>
#include <hip/hip_bf16.h>
#include <hip/hip_fp16.h>
#include <float.h>
#include <limits.h>

#define NROWS 131072
#define DIM   256
#define NLVL  4
#define KC    1024
#define AMB_MARGIN 6.0f  // fp32 ambiguity test (validated r4-r9)
#define MARGIN 7.0f      // g8 expansion: 6 + 1 fp16/RTN slack (validated r8/r9)
#define GUARD 0.25f      // parallel-vs-serial fp32 ordering guard (30x worst-case err)
#define CAP   64

typedef __attribute__((ext_vector_type(8))) short bf16x8;
typedef __attribute__((ext_vector_type(4))) float f32x4;
typedef __attribute__((ext_vector_type(4))) unsigned short us4;

__device__ __forceinline__ unsigned short f2b(float f){
  __hip_bfloat16 h = __float2bfloat16(f);
  return *reinterpret_cast<unsigned short*>(&h);
}

__device__ __forceinline__ float sqb(float x){
  float s = x * x;
  asm volatile("" : "+v"(s));
  return s;
}

__device__ __forceinline__ void upd2(float& m1, int& i1, float& m2, float s, int ci){
  const bool lt = s < m1;
  m2 = lt ? m1 : fminf(m2, s);
  i1 = lt ? ci : i1;
  m1 = lt ? s : m1;
}

__device__ __forceinline__ void merge2(float& m1, int& i1, float& m2,
                                       float om1, int oi1, float om2){
  if (om1 < m1 || (om1 == m1 && oi1 < i1)){
    m2 = fminf(m1, om2); m1 = om1; i1 = oi1;
  } else {
    m2 = fminf(m2, om1);
  }
}

// ---------------- prep kernels (validated r4-r9) ------------------------
__global__ void zero4(int* __restrict__ p){
  if (threadIdx.x < 4) p[threadIdx.x] = 0;
}

__global__ void prep_cbb(const float* __restrict__ cb, unsigned short* __restrict__ cbb){
  const int wave = threadIdx.x >> 6, lane = threadIdx.x & 63;
  const int c = blockIdx.x * 4 + wave;
  const size_t off = (size_t)c * DIM + lane * 4;
  const float4 v = *reinterpret_cast<const float4*>(cb + off);
  us4 u = { f2b(v.x), f2b(v.y), f2b(v.z), f2b(v.w) };
  *reinterpret_cast<us4*>(cbb + off) = u;
}

__global__ void prep_cn(const float* __restrict__ cb, float* __restrict__ cnx){
  const int c = blockIdx.x * 64 + threadIdx.x;
  const float* p = cb + (size_t)c * DIM;
  float blk[2];
  for (int b = 0; b < 2; ++b){
    float r[8];
#pragma unroll
    for (int j = 0; j < 8; ++j) r[j] = sqb(p[b*128 + j]);
    for (int i = 8; i < 128; i += 8)
#pragma unroll
      for (int j = 0; j < 8; ++j) r[j] += sqb(p[b*128 + i + j]);
    blk[b] = ((r[0]+r[1]) + (r[2]+r[3])) + ((r[4]+r[5]) + (r[6]+r[7]));
  }
  cnx[c] = blk[0] + blk[1];
}

// ---------------- K1: LDS-tiled GEMM + g8min + top-2 classify -----------
// verbatim r9 (validated, absmax 0.0).
template<int LVL>
__global__ __launch_bounds__(512, 4)
void rvq_score(const float* __restrict__ feat,
               const float* __restrict__ cb32,
               const unsigned short* __restrict__ cbb_l,
               const float* __restrict__ cnx_l,
               int* __restrict__ idxw,
               unsigned short* __restrict__ g8buf,
               int* __restrict__ ambcnt,
               int* __restrict__ ambrows)
{
  __shared__ __align__(16) char smem[81920];
  unsigned short* Bs  = (unsigned short*)smem;            // 32 KB
  unsigned short* As  = (unsigned short*)(smem + 32768);  // 32 KB (2 bufs)
  unsigned short* g8s = (unsigned short*)(smem + 65536);  // 16 KB
  float* wm1 = (float*)(smem + 32768);
  int*   wi1 = (int*)  (smem + 32768 + 1024);
  float* wm2 = (float*)(smem + 32768 + 2048);
  int*   alist = (int*)(smem + 32768 + 3072);
  int*   acnt_s = (int*)(smem + 32768 + 3328);
  int*   abase_s = (int*)(smem + 32768 + 3344);

  const int tid  = threadIdx.x;
  const int lane = tid & 63;
  const int wave = tid >> 6;
  const int r16  = lane & 15, quad = lane >> 4;
  const int wr   = wave >> 2, wc = wave & 3;
  const int rowbase = (int)blockIdx.x * 64;

  bf16x8 s0, s1;
  {
#pragma unroll
    for (int it = 0; it < 2; ++it){
      const int i = it*512 + tid, r = i >> 2, c = i & 3;
      const bf16x8 v = *reinterpret_cast<const bf16x8*>(
          cbb_l + (size_t)r * DIM + ((c ^ (r & 3)) << 3));
      if (it == 0) s0 = v; else s1 = v;
    }
  }

  {
    const int row = tid >> 3;
    const int d0 = (tid & 7) * 32;
    const int grow = rowbase + row;
    int hist[NLVL > 1 ? NLVL : 1];
#pragma unroll
    for (int j = 0; j < LVL; ++j) hist[j] = idxw[j * NROWS + grow];
#pragma unroll
    for (int c4 = 0; c4 < 4; ++c4){
      const int d = d0 + c4*8;
      const float* p = feat + (size_t)grow * DIM + d;
      float4 f0 = *reinterpret_cast<const float4*>(p);
      float4 f1 = *reinterpret_cast<const float4*>(p + 4);
#pragma unroll
      for (int j = 0; j < LVL; ++j){
        const float* cp = cb32 + ((size_t)j * KC + hist[j]) * DIM + d;
        const float4 c0 = *reinterpret_cast<const float4*>(cp);
        const float4 c1 = *reinterpret_cast<const float4*>(cp + 4);
        f0.x -= c0.x; f0.y -= c0.y; f0.z -= c0.z; f0.w -= c0.w;
        f1.x -= c1.x; f1.y -= c1.y; f1.z -= c1.z; f1.w -= c1.w;
      }
      bf16x8 b;
      b[0]=(short)f2b(f0.x); b[1]=(short)f2b(f0.y); b[2]=(short)f2b(f0.z); b[3]=(short)f2b(f0.w);
      b[4]=(short)f2b(f1.x); b[5]=(short)f2b(f1.y); b[6]=(short)f2b(f1.z); b[7]=(short)f2b(f1.w);
      *reinterpret_cast<bf16x8*>(&Bs[row*256 + (((d >> 3) ^ (row & 7)) << 3)]) = b;
    }
  }

  f32x4 acc[2][4];
#pragma unroll
  for (int mi = 0; mi < 2; ++mi)
#pragma unroll
    for (int ni = 0; ni < 4; ++ni) acc[mi][ni] = (f32x4){0.f,0.f,0.f,0.f};

  float t1[2] = { FLT_MAX, FLT_MAX }, t2[2] = { FLT_MAX, FLT_MAX };
  int   ti[2] = { INT_MAX, INT_MAX };

  int buf = 0;
  for (int i = 0; i < 32; ++i){
    const int ct = i >> 3, kt = i & 7;
    __syncthreads();
    {
      const int i0 = tid, r0 = i0 >> 2, c0 = i0 & 3;
      *reinterpret_cast<bf16x8*>(&As[buf*8192 + r0*32 + (c0 << 3)]) = s0;
      const int i1 = 512 + tid, r1 = i1 >> 2, c1 = i1 & 3;
      *reinterpret_cast<bf16x8*>(&As[buf*8192 + r1*32 + (c1 << 3)]) = s1;
    }
    if (i < 31){
      const int ni2 = i + 1, nct = ni2 >> 3, nkt = ni2 & 7;
#pragma unroll
      for (int it = 0; it < 2; ++it){
        const int ii = it*512 + tid, r = ii >> 2, c = ii & 3;
        const bf16x8 v = *reinterpret_cast<const bf16x8*>(
            cbb_l + (size_t)(nct*256 + r) * DIM + nkt*32 + ((c ^ (r & 3)) << 3));
        if (it == 0) s0 = v; else s1 = v;
      }
    }
    __syncthreads();

    bf16x8 Bf[2], Af[4];
#pragma unroll
    for (int mi = 0; mi < 2; ++mi){
      const int row = wr*32 + mi*16 + r16;
      Bf[mi] = *reinterpret_cast<const bf16x8*>(
          &Bs[row*256 + (((kt*4 + quad) ^ (row & 7)) << 3)]);
    }
#pragma unroll
    for (int ni = 0; ni < 4; ++ni){
      const int arow = wc*64 + ni*16 + r16;
      Af[ni] = *reinterpret_cast<const bf16x8*>(
          &As[buf*8192 + arow*32 + ((quad ^ (arow & 3)) << 3)]);
    }
#pragma unroll
    for (int ni = 0; ni < 4; ++ni){
      acc[0][ni] = __builtin_amdgcn_mfma_f32_16x16x32_bf16(Af[ni], Bf[0], acc[0][ni], 0, 0, 0);
      acc[1][ni] = __builtin_amdgcn_mfma_f32_16x16x32_bf16(Af[ni], Bf[1], acc[1][ni], 0, 0, 0);
    }

    if (kt == 7){
#pragma unroll
      for (int mi = 0; mi < 2; ++mi)
#pragma unroll
        for (int ni = 0; ni < 4; ++ni){
          const int c0 = ct*256 + wc*64 + ni*16 + quad*4;
          const float4 cn = *reinterpret_cast<const float4*>(cnx_l + c0);
          const f32x4 a = acc[mi][ni];
          const float s0v = cn.x - 2.f*a[0];
          const float s1v = cn.y - 2.f*a[1];
          const float s2v = cn.z - 2.f*a[2];
          const float s3v = cn.w - 2.f*a[3];
          upd2(t1[mi], ti[mi], t2[mi], s0v, c0+0);
          upd2(t1[mi], ti[mi], t2[mi], s1v, c0+1);
          upd2(t1[mi], ti[mi], t2[mi], s2v, c0+2);
          upd2(t1[mi], ti[mi], t2[mi], s3v, c0+3);
          const float m4 = fminf(fminf(s0v, s1v), fminf(s2v, s3v));
          const float m8 = fminf(m4, __shfl_xor(m4, 16));
          if ((quad & 1) == 0){
            const int row = wr*32 + mi*16 + r16;
            const int col = c0 >> 3;
            const __half h = __float2half(m8);
            g8s[row*128 + (col ^ ((row & 7) << 3))] =
                __builtin_bit_cast(unsigned short, h);
          }
          acc[mi][ni] = (f32x4){0.f,0.f,0.f,0.f};
        }
    }
    buf ^= 1;
  }

  __syncthreads();

#pragma unroll
  for (int it = 0; it < 2; ++it){
    const int i = it*512 + tid;
    const int row = i >> 4, ch = i & 15;
    const uint4 v = *reinterpret_cast<const uint4*>(
        &g8s[row*128 + ((ch*8) ^ ((row & 7) << 3))]);
    *reinterpret_cast<uint4*>(g8buf + (size_t)(rowbase + row)*128 + ch*8) = v;
  }
#pragma unroll
  for (int mi = 0; mi < 2; ++mi){
    float m1 = t1[mi], m2 = t2[mi]; int i1 = ti[mi];
    merge2(m1, i1, m2, __shfl_xor(m1,16), __shfl_xor(i1,16), __shfl_xor(m2,16));
    merge2(m1, i1, m2, __shfl_xor(m1,32), __shfl_xor(i1,32), __shfl_xor(m2,32));
    if (quad == 0){
      const int row = wr*32 + mi*16 + r16;
      wm1[row*4 + wc] = m1; wi1[row*4 + wc] = i1; wm2[row*4 + wc] = m2;
    }
  }
  if (tid == 0) *acnt_s = 0;
  __syncthreads();

  if (tid < 64){
    float m1 = wm1[tid*4]; int i1 = wi1[tid*4]; float m2 = wm2[tid*4];
#pragma unroll
    for (int w = 1; w < 4; ++w)
      merge2(m1, i1, m2, wm1[tid*4+w], wi1[tid*4+w], wm2[tid*4+w]);
    if (m2 - m1 > AMB_MARGIN){
      idxw[LVL * NROWS + rowbase + tid] = i1;
    } else {
      alist[atomicAdd(acnt_s, 1)] = tid;
    }
  }
  __syncthreads();
  if (tid == 0) *abase_s = atomicAdd(&ambcnt[LVL], *acnt_s);
  __syncthreads();
  if (tid < *acnt_s) ambrows[*abase_s + tid] = rowbase + alist[tid];
}

// ---------------- K2: guarded parallel rescore of ambiguous rows --------
// 16 lanes cooperate per candidate (coalesced 1KB loads, 16-fmaf + butterfly);
// parallel top-2 gap > GUARD proves the np-fp32 argmin; else serial-exact
// fallback (verbatim r4-validated chain) over near candidates.
template<int LVL>
__global__ __launch_bounds__(256)
void rvq_rerank(const float* __restrict__ feat,
                const float* __restrict__ cb32,
                const float* __restrict__ cnx_l,
                int* __restrict__ idxw,
                const unsigned short* __restrict__ g8buf,
                const int* __restrict__ ambcnt,
                const int* __restrict__ ambrows)
{
  __shared__ float rres[16][260];
  __shared__ int rcnt[16];
  __shared__ int rcand[16][CAP];
  __shared__ int ncnt[16];
  __shared__ int nlist[16][CAP];
  const int tid = threadIdx.x;
  const int g = tid >> 4, q = tid & 15;
  const int cnt = ambcnt[LVL];
  const float* cbl = cb32 + (size_t)LVL * KC * DIM;

  for (int rr = blockIdx.x * 16 + g; rr < cnt; rr += gridDim.x * 16){
    const int grow = ambrows[rr];
    if (q == 0){ rcnt[g] = 0; ncnt[g] = 0; }

    // ---- g8 threshold + candidate supersets (validated r8/r9) ----------
    const uint4 u = *reinterpret_cast<const uint4*>(g8buf + (size_t)grow*128 + q*8);
    const unsigned uu[4] = { u.x, u.y, u.z, u.w };
    float v[8];
#pragma unroll
    for (int e = 0; e < 8; ++e){
      const unsigned short hv = (unsigned short)(uu[e >> 1] >> ((e & 1) * 16));
      v[e] = __half2float(__builtin_bit_cast(__half, hv));
    }
    float mn = v[0];
#pragma unroll
    for (int e = 1; e < 8; ++e) mn = fminf(mn, v[e]);
#pragma unroll
    for (int m = 1; m < 16; m <<= 1) mn = fminf(mn, __shfl_xor(mn, m));
    const float thr = mn + MARGIN;

#pragma unroll
    for (int e = 0; e < 8; ++e){
      if (v[e] <= thr){
        const int pos = atomicAdd(&rcnt[g], 8);
        const int base = (q*8 + e) * 8;
#pragma unroll
        for (int e2 = 0; e2 < 8; ++e2)
          if (pos + e2 < CAP) rcand[g][pos + e2] = base + e2;
      }
    }

    // ---- residual: exact fp32 chain -> registers + LDS stash -----------
    float4 rv[4];
#pragma unroll
    for (int i4 = 0; i4 < 4; ++i4){
      const int d = q*16 + i4*4;
      float4 w = *reinterpret_cast<const float4*>(feat + (size_t)grow * DIM + d);
#pragma unroll
      for (int j2 = 0; j2 < LVL; ++j2){
        const int kj = idxw[(size_t)j2 * NROWS + grow];
        const float4 cv = *reinterpret_cast<const float4*>(
            cb32 + ((size_t)j2 * KC + kj) * DIM + d);
        w.x -= cv.x; w.y -= cv.y; w.z -= cv.z; w.w -= cv.w;
      }
      rv[i4] = w;
      *reinterpret_cast<float4*>(&rres[g][d]) = w;
    }

    // ---- pass 1: parallel scores, group top-2 ---------------------------
    const int c = rcnt[g];
    const bool brute = (c > CAP);
    const int ncand = brute ? KC : c;
    float m1 = FLT_MAX, m2 = FLT_MAX; int i1 = INT_MAX;
    for (int qq = 0; qq < ncand; ++qq){
      const int ci = brute ? qq : rcand[g][qq];
      const float* cp = cbl + (size_t)ci * DIM + q*16;
      float pa = 0.f;
#pragma unroll
      for (int j = 0; j < 4; ++j){
        const float4 cv = *reinterpret_cast<const float4*>(cp + j*4);
        pa = fmaf(rv[j].x, cv.x, pa); pa = fmaf(rv[j].y, cv.y, pa);
        pa = fmaf(rv[j].z, cv.z, pa); pa = fmaf(rv[j].w, cv.w, pa);
      }
#pragma unroll
      for (int m = 1; m < 16; m <<= 1) pa += __shfl_xor(pa, m);
      const float sc = cnx_l[ci] - 2.0f * pa;
      if (sc < m1 || (sc == m1 && ci < i1)){ m2 = m1; m1 = sc; i1 = ci; }
      else m2 = fminf(m2, sc);
    }

    int winner = i1;
    if (!(m2 - m1 > GUARD)){
      // ---- pass 2: collect near candidates (parallel score <= m1+GUARD)
      for (int qq = 0; qq < ncand; ++qq){
        const int ci = brute ? qq : rcand[g][qq];
        const float* cp = cbl + (size_t)ci * DIM + q*16;
        float pa = 0.f;
#pragma unroll
        for (int j = 0; j < 4; ++j){
          const float4 cv = *reinterpret_cast<const float4*>(cp + j*4);
          pa = fmaf(rv[j].x, cv.x, pa); pa = fmaf(rv[j].y, cv.y, pa);
          pa = fmaf(rv[j].z, cv.z, pa); pa = fmaf(rv[j].w, cv.w, pa);
        }
#pragma unroll
        for (int m = 1; m < 16; m <<= 1) pa += __shfl_xor(pa, m);
        const float sc = cnx_l[ci] - 2.0f * pa;
        if (sc <= m1 + GUARD && q == 0){
          const int pos = ncnt[g]; ncnt[g] = pos + 1;
          if (pos < CAP) nlist[g][pos] = ci;
        }
      }
      const int nc0 = ncnt[g];
      const bool nover = (nc0 > CAP);
      const int nc = nover ? ncand : nc0;
      // ---- serial-exact rescore (verbatim r4-validated chain) -----------
      float bs = FLT_MAX; int bi = INT_MAX;
      for (int k = q; k < nc; k += 16){
        const int ci = nover ? (brute ? k : rcand[g][k]) : nlist[g][k];
        float a = 0.f;
        for (int d4 = 0; d4 < 64; ++d4){
          const float4 cv = *reinterpret_cast<const float4*>(cbl + (size_t)ci * DIM + d4*4);
          const float4 rw = *reinterpret_cast<const float4*>(&rres[g][d4*4]);
          a = fmaf(rw.x, cv.x, a); a = fmaf(rw.y, cv.y, a);
          a = fmaf(rw.z, cv.z, a); a = fmaf(rw.w, cv.w, a);
        }
        const float sc = cnx_l[ci] - 2.0f * a;
        if (sc < bs || (sc == bs && ci < bi)){ bs = sc; bi = ci; }
      }
#pragma unroll
      for (int m = 1; m < 16; m <<= 1){
        const float ob = __shfl_xor(bs, m); const int oi = __shfl_xor(bi, m);
        if (ob < bs || (ob == bs && oi < bi)){ bs = ob; bi = oi; }
      }
      winner = bi;
    }
    if (q == 0) idxw[(size_t)LVL * NROWS + grow] = winner;
  }
}

// ---------------- K3: final output = q0+q1+q2+q3 (validated r5-r9) ------
__global__ __launch_bounds__(256)
void rvq_out(const float* __restrict__ cb32,
             const int* __restrict__ idxw,
             float* __restrict__ out)
{
  const int tid = threadIdx.x;
  const int row = tid >> 4, sub = tid & 15;
  const size_t n = (size_t)blockIdx.x * 16 + row;
  int hist[NLVL];
#pragma unroll
  for (int j2 = 0; j2 < 4; ++j2) hist[j2] = idxw[(size_t)j2 * NROWS + n];
#pragma unroll
  for (int i = 0; i < 4; ++i){
    const int d = sub*4 + i*64;
    float4 a = *reinterpret_cast<const float4*>(
        cb32 + ((size_t)0 * KC + hist[0]) * DIM + d);
#pragma unroll
    for (int j2 = 1; j2 < 4; ++j2){
      const float4 qv = *reinterpret_cast<const float4*>(
          cb32 + ((size_t)j2 * KC + hist[j2]) * DIM + d);
      a.x += qv.x; a.y += qv.y; a.z += qv.z; a.w += qv.w;
    }
    *reinterpret_cast<float4*>(out + n*DIM + d) = a;
  }
}

extern "C" void kernel_launch(void* const* d_in, const int* in_sizes, int n_in,
                              void* d_out, int out_size, void* d_ws, size_t ws_size,
                              hipStream_t stream){
  const float* feat = (const float*)d_in[0];
  const float* cb32 = (const float*)d_in[1];
  float* out = (float*)d_out;

  char* ws = (char*)d_ws;
  float* cnx = (float*)(ws);                                   // 16 KB
  int*   amb = (int*)(ws + 16384);                             // 4 counters
  unsigned short* cbb  = (unsigned short*)(ws + 32768);        // 2 MB
  int*   idxw = (int*)(ws + 32768 + 2097152);                  // 2 MB
  int*   ambrows = (int*)(ws + 32768 + 2097152 + 2097152);     // 512 KB
  unsigned short* g8buf = (unsigned short*)(ws + 32768 + 2097152 + 2097152 + 524288); // 33.5 MB

  zero4<<<1, 64, 0, stream>>>(amb);
  prep_cbb<<<1024, 256, 0, stream>>>(cb32, cbb);
  prep_cn<<<64, 64, 0, stream>>>(cb32, cnx);

#define LVL_STEP(L) \
  rvq_score<L><<<2048, 512, 0, stream>>>(feat, cb32, cbb + (size_t)L*KC*DIM, \
      cnx + L*KC, idxw, g8buf, amb, ambrows); \
  rvq_rerank<L><<<2048, 256, 0, stream>>>(feat, cb32, cnx + L*KC, idxw, g8buf, amb, ambrows);

  LVL_STEP(0)
  LVL_STEP(1)
  LVL_STEP(2)
  LVL_STEP(3)
#undef LVL_STEP

  rvq_out<<<8192, 256, 0, stream>>>(cb32, idxw, out);
}

// Round 11
// 2558.132 us; speedup vs baseline: 1.6481x; 1.6481x over previous
//
#include <hip/hip_runtime.h>
#include <hip/hip_bf16.h>
#include <float.h>
#include <limits.h>

#define NROWS 131072
#define DIM   256
#define NLVL  4
#define KC    1024
#define AMB   6.0f     // bf16-score ambiguity margin (validated r4-r10)
#define GUARD 0.25f    // parallel-vs-serial fp32 ordering guard (validated r10)

typedef __attribute__((ext_vector_type(8))) short bf16x8;
typedef __attribute__((ext_vector_type(4))) float f32x4;
typedef __attribute__((ext_vector_type(4))) unsigned short us4;

__device__ __forceinline__ unsigned short f2b(float f){
  __hip_bfloat16 h = __float2bfloat16(f);
  return *reinterpret_cast<unsigned short*>(&h);
}

__device__ __forceinline__ float sqb(float x){
  float s = x * x;
  asm volatile("" : "+v"(s));
  return s;
}

__device__ __forceinline__ bool sless(float a, int ia, float b, int ib){
  return a < b || (a == b && ia < ib);
}

// strict-< top-4 insert (tie-correct for ascending-index streams)
__device__ __forceinline__ void ins4(float (&s)[4], int (&ix)[4], float v, int ci){
  if (v < s[3]){
    s[3]=v; ix[3]=ci;
#pragma unroll
    for (int j = 3; j >= 1; --j){
      if (s[j] < s[j-1]){
        float t=s[j-1]; s[j-1]=s[j]; s[j]=t;
        int u=ix[j-1]; ix[j-1]=ix[j]; ix[j]=u;
      }
    }
  }
}

// tie-aware top-4 insert (for cross-lane merges)
__device__ __forceinline__ void ins4t(float (&s)[4], int (&ix)[4], float v, int ci){
  if (sless(v, ci, s[3], ix[3])){
    s[3]=v; ix[3]=ci;
#pragma unroll
    for (int j = 3; j >= 1; --j){
      if (sless(s[j], ix[j], s[j-1], ix[j-1])){
        float t=s[j-1]; s[j-1]=s[j]; s[j]=t;
        int u=ix[j-1]; ix[j-1]=ix[j]; ix[j]=u;
      }
    }
  }
}

// ---------------- prep kernels (validated r4-r10) -----------------------
__global__ void zero8(int* __restrict__ p){
  if (threadIdx.x < 8) p[threadIdx.x] = 0;
}

__global__ void prep_cbb(const float* __restrict__ cb, unsigned short* __restrict__ cbb){
  const int wave = threadIdx.x >> 6, lane = threadIdx.x & 63;
  const int c = blockIdx.x * 4 + wave;
  const size_t off = (size_t)c * DIM + lane * 4;
  const float4 v = *reinterpret_cast<const float4*>(cb + off);
  us4 u = { f2b(v.x), f2b(v.y), f2b(v.z), f2b(v.w) };
  *reinterpret_cast<us4*>(cbb + off) = u;
}

__global__ void prep_cn(const float* __restrict__ cb, float* __restrict__ cnx){
  const int c = blockIdx.x * 64 + threadIdx.x;
  const float* p = cb + (size_t)c * DIM;
  float blk[2];
  for (int b = 0; b < 2; ++b){
    float r[8];
#pragma unroll
    for (int j = 0; j < 8; ++j) r[j] = sqb(p[b*128 + j]);
    for (int i = 8; i < 128; i += 8)
#pragma unroll
      for (int j = 0; j < 8; ++j) r[j] += sqb(p[b*128 + i + j]);
    blk[b] = ((r[0]+r[1]) + (r[2]+r[3])) + ((r[4]+r[5]) + (r[6]+r[7]));
  }
  cnx[c] = blk[0] + blk[1];
}

// ---------------- K1: LDS-tiled GEMM (r8/r9 validated) + top-4 classify --
// 64 rows/block, 8 waves (2x4), wave tile 32 rows x 64 centers.
// Per-lane top-4 -> quad/wave merges -> gap>6 done | amb4 | hard.
template<int LVL>
__global__ __launch_bounds__(512, 4)
void rvq_score(const float* __restrict__ feat,
               const float* __restrict__ cb32,
               const unsigned short* __restrict__ cbb_l,
               const float* __restrict__ cnx_l,
               int* __restrict__ idxw,
               int* __restrict__ cnt8,      // [0..3] amb4, [4..7] hard
               int* __restrict__ arecs,     // [*][5]: row, i0..i3
               int* __restrict__ hrows)
{
  __shared__ __align__(16) char smem[65536];
  unsigned short* Bs = (unsigned short*)smem;            // 32 KB
  unsigned short* As = (unsigned short*)(smem + 32768);  // 32 KB (2 bufs)
  float* wts = (float*)(smem + 32768);                   // alias (4 KB)
  int*   wti = (int*)  (smem + 32768 + 4096);            // alias (4 KB)
  __shared__ int acnt_s, hcnt_s, abase_s, hbase_s;

  const int tid  = threadIdx.x;
  const int lane = tid & 63;
  const int wave = tid >> 6;
  const int r16  = lane & 15, quad = lane >> 4;
  const int wr   = wave >> 2, wc = wave & 3;
  const int rowbase = (int)blockIdx.x * 64;

  if (tid == 0){ acnt_s = 0; hcnt_s = 0; }

  // ---- A tile 0 reg-stage (overlaps B build) ---------------------------
  bf16x8 s0, s1;
  {
#pragma unroll
    for (int it = 0; it < 2; ++it){
      const int i = it*512 + tid, r = i >> 2, c = i & 3;
      const bf16x8 v = *reinterpret_cast<const bf16x8*>(
          cbb_l + (size_t)r * DIM + ((c ^ (r & 3)) << 3));
      if (it == 0) s0 = v; else s1 = v;
    }
  }

  // ---- phase 0: residual rows -> LDS (exact fp32 chain -> bf16) --------
  {
    const int row = tid >> 3;
    const int d0 = (tid & 7) * 32;
    const int grow = rowbase + row;
    int hist[NLVL > 1 ? NLVL : 1];
#pragma unroll
    for (int j = 0; j < LVL; ++j) hist[j] = idxw[j * NROWS + grow];
#pragma unroll
    for (int c4 = 0; c4 < 4; ++c4){
      const int d = d0 + c4*8;
      const float* p = feat + (size_t)grow * DIM + d;
      float4 f0 = *reinterpret_cast<const float4*>(p);
      float4 f1 = *reinterpret_cast<const float4*>(p + 4);
#pragma unroll
      for (int j = 0; j < LVL; ++j){
        const float* cp = cb32 + ((size_t)j * KC + hist[j]) * DIM + d;
        const float4 c0 = *reinterpret_cast<const float4*>(cp);
        const float4 c1 = *reinterpret_cast<const float4*>(cp + 4);
        f0.x -= c0.x; f0.y -= c0.y; f0.z -= c0.z; f0.w -= c0.w;
        f1.x -= c1.x; f1.y -= c1.y; f1.z -= c1.z; f1.w -= c1.w;
      }
      bf16x8 b;
      b[0]=(short)f2b(f0.x); b[1]=(short)f2b(f0.y); b[2]=(short)f2b(f0.z); b[3]=(short)f2b(f0.w);
      b[4]=(short)f2b(f1.x); b[5]=(short)f2b(f1.y); b[6]=(short)f2b(f1.z); b[7]=(short)f2b(f1.w);
      *reinterpret_cast<bf16x8*>(&Bs[row*256 + (((d >> 3) ^ (row & 7)) << 3)]) = b;
    }
  }

  f32x4 acc[2][4];
#pragma unroll
  for (int mi = 0; mi < 2; ++mi)
#pragma unroll
    for (int ni = 0; ni < 4; ++ni) acc[mi][ni] = (f32x4){0.f,0.f,0.f,0.f};

  float ts[2][4] = {{FLT_MAX,FLT_MAX,FLT_MAX,FLT_MAX},{FLT_MAX,FLT_MAX,FLT_MAX,FLT_MAX}};
  int   ti[2][4] = {{INT_MAX,INT_MAX,INT_MAX,INT_MAX},{INT_MAX,INT_MAX,INT_MAX,INT_MAX}};

  int buf = 0;
  for (int i = 0; i < 32; ++i){
    const int ct = i >> 3, kt = i & 7;
    __syncthreads();
    {
      const int i0 = tid, r0 = i0 >> 2, c0 = i0 & 3;
      *reinterpret_cast<bf16x8*>(&As[buf*8192 + r0*32 + (c0 << 3)]) = s0;
      const int i1 = 512 + tid, r1 = i1 >> 2, c1 = i1 & 3;
      *reinterpret_cast<bf16x8*>(&As[buf*8192 + r1*32 + (c1 << 3)]) = s1;
    }
    if (i < 31){
      const int ni2 = i + 1, nct = ni2 >> 3, nkt = ni2 & 7;
#pragma unroll
      for (int it = 0; it < 2; ++it){
        const int ii = it*512 + tid, r = ii >> 2, c = ii & 3;
        const bf16x8 v = *reinterpret_cast<const bf16x8*>(
            cbb_l + (size_t)(nct*256 + r) * DIM + nkt*32 + ((c ^ (r & 3)) << 3));
        if (it == 0) s0 = v; else s1 = v;
      }
    }
    __syncthreads();

    bf16x8 Bf[2], Af[4];
#pragma unroll
    for (int mi = 0; mi < 2; ++mi){
      const int row = wr*32 + mi*16 + r16;
      Bf[mi] = *reinterpret_cast<const bf16x8*>(
          &Bs[row*256 + (((kt*4 + quad) ^ (row & 7)) << 3)]);
    }
#pragma unroll
    for (int ni = 0; ni < 4; ++ni){
      const int arow = wc*64 + ni*16 + r16;
      Af[ni] = *reinterpret_cast<const bf16x8*>(
          &As[buf*8192 + arow*32 + ((quad ^ (arow & 3)) << 3)]);
    }
#pragma unroll
    for (int ni = 0; ni < 4; ++ni){
      acc[0][ni] = __builtin_amdgcn_mfma_f32_16x16x32_bf16(Af[ni], Bf[0], acc[0][ni], 0, 0, 0);
      acc[1][ni] = __builtin_amdgcn_mfma_f32_16x16x32_bf16(Af[ni], Bf[1], acc[1][ni], 0, 0, 0);
    }

    if (kt == 7){
#pragma unroll
      for (int mi = 0; mi < 2; ++mi)
#pragma unroll
        for (int ni = 0; ni < 4; ++ni){
          const int c0 = ct*256 + wc*64 + ni*16 + quad*4;
          const float4 cn = *reinterpret_cast<const float4*>(cnx_l + c0);
          const f32x4 a = acc[mi][ni];
          ins4(ts[mi], ti[mi], cn.x - 2.f*a[0], c0+0);
          ins4(ts[mi], ti[mi], cn.y - 2.f*a[1], c0+1);
          ins4(ts[mi], ti[mi], cn.z - 2.f*a[2], c0+2);
          ins4(ts[mi], ti[mi], cn.w - 2.f*a[3], c0+3);
          acc[mi][ni] = (f32x4){0.f,0.f,0.f,0.f};
        }
    }
    buf ^= 1;
  }

  __syncthreads();   // As dead from here (aliased by wts/wti)

  // ---- cross-quad merge (tie-aware) + publish per (row, wc) ------------
#pragma unroll
  for (int mi = 0; mi < 2; ++mi){
#pragma unroll
    for (int off = 16; off <= 32; off <<= 1){
      float os[4]; int oi[4];
#pragma unroll
      for (int e = 0; e < 4; ++e){
        os[e] = __shfl_xor(ts[mi][e], off);
        oi[e] = __shfl_xor(ti[mi][e], off);
      }
#pragma unroll
      for (int e = 0; e < 4; ++e) ins4t(ts[mi], ti[mi], os[e], oi[e]);
    }
    if (quad == 0){
      const int row = wr*32 + mi*16 + r16;
#pragma unroll
      for (int e = 0; e < 4; ++e){
        wts[(row*4 + wc)*4 + e] = ts[mi][e];
        wti[(row*4 + wc)*4 + e] = ti[mi][e];
      }
    }
  }
  __syncthreads();

  // ---- per-row final merge + classify -----------------------------------
  int apos = -1, hpos = -1;
  float fs[4]; int fx[4];
  if (tid < 64){
#pragma unroll
    for (int e = 0; e < 4; ++e){ fs[e] = wts[(tid*4)*4 + e]; fx[e] = wti[(tid*4)*4 + e]; }
#pragma unroll
    for (int w = 1; w < 4; ++w)
#pragma unroll
      for (int e = 0; e < 4; ++e)
        ins4t(fs, fx, wts[(tid*4 + w)*4 + e], wti[(tid*4 + w)*4 + e]);
    if (fs[1] - fs[0] > AMB){
      idxw[LVL * NROWS + rowbase + tid] = fx[0];
    } else if (fs[3] - fs[0] > AMB){
      apos = atomicAdd(&acnt_s, 1);
    } else {
      hpos = atomicAdd(&hcnt_s, 1);
    }
  }
  __syncthreads();
  if (tid == 0){
    abase_s = acnt_s ? atomicAdd(&cnt8[LVL], acnt_s) : 0;
    hbase_s = hcnt_s ? atomicAdd(&cnt8[4 + LVL], hcnt_s) : 0;
  }
  __syncthreads();
  if (apos >= 0){
    int* rp = arecs + (size_t)(abase_s + apos) * 5;
    rp[0] = rowbase + tid;
    rp[1] = fx[0]; rp[2] = fx[1]; rp[3] = fx[2]; rp[4] = fx[3];
  }
  if (hpos >= 0) hrows[hbase_s + hpos] = rowbase + tid;
}

// ---------------- K2a: amb4 rows — 4 parallel dots, GUARD, rare serial --
template<int LVL>
__global__ __launch_bounds__(256)
void rvq_amb4(const float* __restrict__ feat,
              const float* __restrict__ cb32,
              const float* __restrict__ cnx_l,
              int* __restrict__ idxw,
              const int* __restrict__ cnt8,
              const int* __restrict__ arecs)
{
  __shared__ float rres[16][260];
  const int tid = threadIdx.x;
  const int g = tid >> 4, q = tid & 15;
  const int cnt = cnt8[LVL];
  const float* cbl = cb32 + (size_t)LVL * KC * DIM;

  for (int rr = blockIdx.x * 16 + g; rr < cnt; rr += gridDim.x * 16){
    const int* rp = arecs + (size_t)rr * 5;
    const int grow = rp[0];
    const int c0 = rp[1], c1 = rp[2], c2 = rp[3], c3 = rp[4];

    // exact fp32-chain residual (validated) -> regs + LDS stash
    float4 rv[4];
#pragma unroll
    for (int i4 = 0; i4 < 4; ++i4){
      const int d = q*16 + i4*4;
      float4 w = *reinterpret_cast<const float4*>(feat + (size_t)grow * DIM + d);
#pragma unroll
      for (int j2 = 0; j2 < LVL; ++j2){
        const int kj = idxw[(size_t)j2 * NROWS + grow];
        const float4 cv = *reinterpret_cast<const float4*>(
            cb32 + ((size_t)j2 * KC + kj) * DIM + d);
        w.x -= cv.x; w.y -= cv.y; w.z -= cv.z; w.w -= cv.w;
      }
      rv[i4] = w;
      *reinterpret_cast<float4*>(&rres[g][d]) = w;
    }

    // 4 unrolled coalesced parallel dots
    float p0 = 0.f, p1 = 0.f, p2 = 0.f, p3 = 0.f;
#pragma unroll
    for (int j = 0; j < 4; ++j){
      const int d = q*16 + j*4;
      const float4 v0 = *reinterpret_cast<const float4*>(cbl + (size_t)c0 * DIM + d);
      const float4 v1 = *reinterpret_cast<const float4*>(cbl + (size_t)c1 * DIM + d);
      const float4 v2 = *reinterpret_cast<const float4*>(cbl + (size_t)c2 * DIM + d);
      const float4 v3 = *reinterpret_cast<const float4*>(cbl + (size_t)c3 * DIM + d);
      p0 = fmaf(rv[j].x, v0.x, p0); p0 = fmaf(rv[j].y, v0.y, p0);
      p0 = fmaf(rv[j].z, v0.z, p0); p0 = fmaf(rv[j].w, v0.w, p0);
      p1 = fmaf(rv[j].x, v1.x, p1); p1 = fmaf(rv[j].y, v1.y, p1);
      p1 = fmaf(rv[j].z, v1.z, p1); p1 = fmaf(rv[j].w, v1.w, p1);
      p2 = fmaf(rv[j].x, v2.x, p2); p2 = fmaf(rv[j].y, v2.y, p2);
      p2 = fmaf(rv[j].z, v2.z, p2); p2 = fmaf(rv[j].w, v2.w, p2);
      p3 = fmaf(rv[j].x, v3.x, p3); p3 = fmaf(rv[j].y, v3.y, p3);
      p3 = fmaf(rv[j].z, v3.z, p3); p3 = fmaf(rv[j].w, v3.w, p3);
    }
#pragma unroll
    for (int m = 1; m < 16; m <<= 1){
      p0 += __shfl_xor(p0, m); p1 += __shfl_xor(p1, m);
      p2 += __shfl_xor(p2, m); p3 += __shfl_xor(p3, m);
    }
    float sc[4]; int cidx[4] = { c0, c1, c2, c3 };
    sc[0] = cnx_l[c0] - 2.0f*p0; sc[1] = cnx_l[c1] - 2.0f*p1;
    sc[2] = cnx_l[c2] - 2.0f*p2; sc[3] = cnx_l[c3] - 2.0f*p3;

    float m1 = sc[0], m2 = FLT_MAX; int i1 = cidx[0];
#pragma unroll
    for (int k = 1; k < 4; ++k){
      if (sless(sc[k], cidx[k], m1, i1)){ m2 = m1; m1 = sc[k]; i1 = cidx[k]; }
      else m2 = fminf(m2, sc[k]);
    }

    int winner = i1;
    if (!(m2 - m1 > GUARD)){
      // serial-exact (validated chain) on the 4 candidates, lanes 0..3
      float bs = FLT_MAX; int bi = INT_MAX;
      if (q < 4){
        const int ci = cidx[q];
        float a = 0.f;
        for (int d4 = 0; d4 < 64; ++d4){
          const float4 cv = *reinterpret_cast<const float4*>(cbl + (size_t)ci * DIM + d4*4);
          const float4 rw = *reinterpret_cast<const float4*>(&rres[g][d4*4]);
          a = fmaf(rw.x, cv.x, a); a = fmaf(rw.y, cv.y, a);
          a = fmaf(rw.z, cv.z, a); a = fmaf(rw.w, cv.w, a);
        }
        bs = cnx_l[ci] - 2.0f * a; bi = ci;
      }
#pragma unroll
      for (int m = 1; m < 16; m <<= 1){
        const float ob = __shfl_xor(bs, m); const int oi = __shfl_xor(bi, m);
        if (sless(ob, oi, bs, bi)){ bs = ob; bi = oi; }
      }
      winner = bi;
    }
    if (q == 0) idxw[(size_t)LVL * NROWS + grow] = winner;
  }
}

// ---------------- K2b: hard rows — block per row, full 1024 + GUARD -----
template<int LVL>
__global__ __launch_bounds__(256)
void rvq_hard(const float* __restrict__ feat,
              const float* __restrict__ cb32,
              const float* __restrict__ cnx_l,
              int* __restrict__ idxw,
              const int* __restrict__ cnt8,
              const int* __restrict__ hrows)
{
  __shared__ float rres[260];
  __shared__ float scb[1024];
  __shared__ float wmn[4];
  __shared__ float wbs[4];
  __shared__ int   wbi[4];
  const int tid = threadIdx.x;
  const int g = tid >> 4, q = tid & 15;
  const int wv = tid >> 6, ln = tid & 63;
  const int cnt = cnt8[4 + LVL];
  const float* cbl = cb32 + (size_t)LVL * KC * DIM;

  for (int r = blockIdx.x; r < cnt; r += gridDim.x){
    const int grow = hrows[r];
    if (tid < 16){
      // exact fp32-chain residual, lane tid owns d = tid*16..+15
#pragma unroll
      for (int i4 = 0; i4 < 4; ++i4){
        const int d = tid*16 + i4*4;
        float4 w = *reinterpret_cast<const float4*>(feat + (size_t)grow * DIM + d);
#pragma unroll
        for (int j2 = 0; j2 < LVL; ++j2){
          const int kj = idxw[(size_t)j2 * NROWS + grow];
          const float4 cv = *reinterpret_cast<const float4*>(
              cb32 + ((size_t)j2 * KC + kj) * DIM + d);
          w.x -= cv.x; w.y -= cv.y; w.z -= cv.z; w.w -= cv.w;
        }
        *reinterpret_cast<float4*>(&rres[d]) = w;
      }
    }
    __syncthreads();

    float4 rv[4];
#pragma unroll
    for (int j = 0; j < 4; ++j)
      rv[j] = *reinterpret_cast<const float4*>(&rres[q*16 + j*4]);

    // all 1024 parallel scores -> LDS (group g covers [g*64, g*64+64))
    for (int t = 0; t < 64; ++t){
      const int ci = g*64 + t;
      float pa = 0.f;
#pragma unroll
      for (int j = 0; j < 4; ++j){
        const float4 cv = *reinterpret_cast<const float4*>(
            cbl + (size_t)ci * DIM + q*16 + j*4);
        pa = fmaf(rv[j].x, cv.x, pa); pa = fmaf(rv[j].y, cv.y, pa);
        pa = fmaf(rv[j].z, cv.z, pa); pa = fmaf(rv[j].w, cv.w, pa);
      }
#pragma unroll
      for (int m = 1; m < 16; m <<= 1) pa += __shfl_xor(pa, m);
      if (q == 0) scb[ci] = cnx_l[ci] - 2.0f * pa;
    }
    __syncthreads();

    // block min (value only)
    float mn = fminf(fminf(scb[tid], scb[tid+256]), fminf(scb[tid+512], scb[tid+768]));
#pragma unroll
    for (int m = 1; m < 64; m <<= 1) mn = fminf(mn, __shfl_xor(mn, m));
    if (ln == 0) wmn[wv] = mn;
    __syncthreads();
    const float m1p = fminf(fminf(wmn[0], wmn[1]), fminf(wmn[2], wmn[3]));
    const float thr = m1p + GUARD;

    // serial-exact every near candidate (each thread checks 4 slots)
    float bs = FLT_MAX; int bi = INT_MAX;
#pragma unroll
    for (int k = 0; k < 4; ++k){
      const int ci = tid + k*256;
      if (scb[ci] <= thr){
        float a = 0.f;
        for (int d4 = 0; d4 < 64; ++d4){
          const float4 cv = *reinterpret_cast<const float4*>(cbl + (size_t)ci * DIM + d4*4);
          const float4 rw = *reinterpret_cast<const float4*>(&rres[d4*4]);
          a = fmaf(rw.x, cv.x, a); a = fmaf(rw.y, cv.y, a);
          a = fmaf(rw.z, cv.z, a); a = fmaf(rw.w, cv.w, a);
        }
        const float sc = cnx_l[ci] - 2.0f * a;
        if (sless(sc, ci, bs, bi)){ bs = sc; bi = ci; }
      }
    }
#pragma unroll
    for (int m = 1; m < 64; m <<= 1){
      const float ob = __shfl_xor(bs, m); const int oi = __shfl_xor(bi, m);
      if (sless(ob, oi, bs, bi)){ bs = ob; bi = oi; }
    }
    if (ln == 0){ wbs[wv] = bs; wbi[wv] = bi; }
    __syncthreads();
    if (tid == 0){
      float fb = wbs[0]; int fi = wbi[0];
#pragma unroll
      for (int w = 1; w < 4; ++w)
        if (sless(wbs[w], wbi[w], fb, fi)){ fb = wbs[w]; fi = wbi[w]; }
      idxw[(size_t)LVL * NROWS + grow] = fi;
    }
    __syncthreads();   // protect rres/scb reuse next iteration
  }
}

// ---------------- K3: final output = q0+q1+q2+q3 (validated r5-r10) -----
__global__ __launch_bounds__(256)
void rvq_out(const float* __restrict__ cb32,
             const int* __restrict__ idxw,
             float* __restrict__ out)
{
  const int tid = threadIdx.x;
  const int row = tid >> 4, sub = tid & 15;
  const size_t n = (size_t)blockIdx.x * 16 + row;
  int hist[NLVL];
#pragma unroll
  for (int j2 = 0; j2 < 4; ++j2) hist[j2] = idxw[(size_t)j2 * NROWS + n];
#pragma unroll
  for (int i = 0; i < 4; ++i){
    const int d = sub*4 + i*64;
    float4 a = *reinterpret_cast<const float4*>(
        cb32 + ((size_t)0 * KC + hist[0]) * DIM + d);
#pragma unroll
    for (int j2 = 1; j2 < 4; ++j2){
      const float4 qv = *reinterpret_cast<const float4*>(
          cb32 + ((size_t)j2 * KC + hist[j2]) * DIM + d);
      a.x += qv.x; a.y += qv.y; a.z += qv.z; a.w += qv.w;
    }
    *reinterpret_cast<float4*>(out + n*DIM + d) = a;
  }
}

extern "C" void kernel_launch(void* const* d_in, const int* in_sizes, int n_in,
                              void* d_out, int out_size, void* d_ws, size_t ws_size,
                              hipStream_t stream){
  const float* feat = (const float*)d_in[0];
  const float* cb32 = (const float*)d_in[1];
  float* out = (float*)d_out;

  char* ws = (char*)d_ws;
  float* cnx  = (float*)(ws);                              // 16 KB
  int*   cnt8 = (int*)(ws + 16384);                        // 8 counters
  unsigned short* cbb = (unsigned short*)(ws + 32768);     // 2 MB
  int*   idxw = (int*)(ws + 32768 + 2097152);              // 2 MB
  int*   arecs = (int*)(ws + 32768 + 2097152 + 2097152);   // 2.75 MB
  int*   hrows = (int*)(ws + 32768 + 2097152 + 2097152 + 2883584); // 512 KB

  zero8<<<1, 64, 0, stream>>>(cnt8);
  prep_cbb<<<1024, 256, 0, stream>>>(cb32, cbb);
  prep_cn<<<64, 64, 0, stream>>>(cb32, cnx);

#define LVL_STEP(L) \
  rvq_score<L><<<2048, 512, 0, stream>>>(feat, cb32, cbb + (size_t)L*KC*DIM, \
      cnx + L*KC, idxw, cnt8, arecs, hrows); \
  rvq_amb4<L><<<2048, 256, 0, stream>>>(feat, cb32, cnx + L*KC, idxw, cnt8, arecs); \
  rvq_hard<L><<<2048, 256, 0, stream>>>(feat, cb32, cnx + L*KC, idxw, cnt8, hrows);

  LVL_STEP(0)
  LVL_STEP(1)
  LVL_STEP(2)
  LVL_STEP(3)
#undef LVL_STEP

  rvq_out<<<8192, 256, 0, stream>>>(cb32, idxw, out);
}

// Round 12
// 1125.301 us; speedup vs baseline: 3.7467x; 2.2733x over previous
//
#include <hip/hip_runtime.h>
#include <hip/hip_bf16.h>
#include <float.h>
#include <limits.h>

#define NROWS 131072
#define DIM   256
#define NLVL  4
#define KC    1024
#define AMB   6.0f     // bf16-score ambiguity margin (validated r4-r11)
#define GUARD 0.25f    // parallel-vs-serial fp32 ordering guard (validated r10/r11)
#define REC   18       // amb record: row, cnt, cand[16]

typedef __attribute__((ext_vector_type(8))) short bf16x8;
typedef __attribute__((ext_vector_type(4))) float f32x4;
typedef __attribute__((ext_vector_type(4))) unsigned short us4;

__device__ __forceinline__ unsigned short f2b(float f){
  __hip_bfloat16 h = __float2bfloat16(f);
  return *reinterpret_cast<unsigned short*>(&h);
}

__device__ __forceinline__ float sqb(float x){
  float s = x * x;
  asm volatile("" : "+v"(s));
  return s;
}

__device__ __forceinline__ bool sless(float a, int ia, float b, int ib){
  return a < b || (a == b && ia < ib);
}

// strict-< top-4 insert (tie-correct for ascending-index per-lane streams)
__device__ __forceinline__ void ins4(float (&s)[4], int (&ix)[4], float v, int ci){
  if (v < s[3]){
    s[3]=v; ix[3]=ci;
#pragma unroll
    for (int j = 3; j >= 1; --j){
      if (s[j] < s[j-1]){
        float t=s[j-1]; s[j-1]=s[j]; s[j]=t;
        int u=ix[j-1]; ix[j-1]=ix[j]; ix[j]=u;
      }
    }
  }
}

// ---------------- prep kernels (validated r4-r11) -----------------------
__global__ void zero8(int* __restrict__ p){
  if (threadIdx.x < 8) p[threadIdx.x] = 0;
}

__global__ void prep_cbb(const float* __restrict__ cb, unsigned short* __restrict__ cbb){
  const int wave = threadIdx.x >> 6, lane = threadIdx.x & 63;
  const int c = blockIdx.x * 4 + wave;
  const size_t off = (size_t)c * DIM + lane * 4;
  const float4 v = *reinterpret_cast<const float4*>(cb + off);
  us4 u = { f2b(v.x), f2b(v.y), f2b(v.z), f2b(v.w) };
  *reinterpret_cast<us4*>(cbb + off) = u;
}

__global__ void prep_cn(const float* __restrict__ cb, float* __restrict__ cnx){
  const int c = blockIdx.x * 64 + threadIdx.x;
  const float* p = cb + (size_t)c * DIM;
  float blk[2];
  for (int b = 0; b < 2; ++b){
    float r[8];
#pragma unroll
    for (int j = 0; j < 8; ++j) r[j] = sqb(p[b*128 + j]);
    for (int i = 8; i < 128; i += 8)
#pragma unroll
      for (int j = 0; j < 8; ++j) r[j] += sqb(p[b*128 + i + j]);
    blk[b] = ((r[0]+r[1]) + (r[2]+r[3])) + ((r[4]+r[5]) + (r[6]+r[7]));
  }
  cnx[c] = blk[0] + blk[1];
}

// ---------------- K1: LDS-tiled GEMM (validated) + lane-top4 classify ---
// 64 rows/block, 8 waves (2x4), wave tile 32 rows x 64 centers. Per-lane
// top-4 of its own 64 centers; rowmin reduce; lanes emit in-margin entries;
// lane-overflow (own 4th-best in margin) -> hard row.
template<int LVL>
__global__ __launch_bounds__(512, 4)
void rvq_score(const float* __restrict__ feat,
               const float* __restrict__ cb32,
               const unsigned short* __restrict__ cbb_l,
               const float* __restrict__ cnx_l,
               int* __restrict__ idxw,
               int* __restrict__ cnt8,      // [0..3] amb, [4..7] hard
               int* __restrict__ arecs,     // [*][REC]
               int* __restrict__ hrows)
{
  __shared__ __align__(16) char smem[65536];
  unsigned short* Bs = (unsigned short*)smem;            // 32 KB
  unsigned short* As = (unsigned short*)(smem + 32768);  // 32 KB (2 bufs)
  // aliases into As region (dead after main loop):
  float* rowm  = (float*)(smem + 32768);                 // [64*4]
  int*   cnt_l = (int*)(smem + 32768 + 1024);            // [64]
  int*   ovf_l = (int*)(smem + 32768 + 1280);            // [64]
  int*   cand_l= (int*)(smem + 32768 + 1536);            // [64*16]
  __shared__ int acnt_s, hcnt_s, abase_s, hbase_s;

  const int tid  = threadIdx.x;
  const int lane = tid & 63;
  const int wave = tid >> 6;
  const int r16  = lane & 15, quad = lane >> 4;
  const int wr   = wave >> 2, wc = wave & 3;
  const int rowbase = (int)blockIdx.x * 64;

  if (tid == 0){ acnt_s = 0; hcnt_s = 0; }

  // ---- A tile 0 reg-stage (overlaps B build) ---------------------------
  bf16x8 s0, s1;
  {
#pragma unroll
    for (int it = 0; it < 2; ++it){
      const int i = it*512 + tid, r = i >> 2, c = i & 3;
      const bf16x8 v = *reinterpret_cast<const bf16x8*>(
          cbb_l + (size_t)r * DIM + ((c ^ (r & 3)) << 3));
      if (it == 0) s0 = v; else s1 = v;
    }
  }

  // ---- phase 0: residual rows -> LDS (exact fp32 chain -> bf16) --------
  {
    const int row = tid >> 3;
    const int d0 = (tid & 7) * 32;
    const int grow = rowbase + row;
    int hist[NLVL > 1 ? NLVL : 1];
#pragma unroll
    for (int j = 0; j < LVL; ++j) hist[j] = idxw[j * NROWS + grow];
#pragma unroll
    for (int c4 = 0; c4 < 4; ++c4){
      const int d = d0 + c4*8;
      const float* p = feat + (size_t)grow * DIM + d;
      float4 f0 = *reinterpret_cast<const float4*>(p);
      float4 f1 = *reinterpret_cast<const float4*>(p + 4);
#pragma unroll
      for (int j = 0; j < LVL; ++j){
        const float* cp = cb32 + ((size_t)j * KC + hist[j]) * DIM + d;
        const float4 c0 = *reinterpret_cast<const float4*>(cp);
        const float4 c1 = *reinterpret_cast<const float4*>(cp + 4);
        f0.x -= c0.x; f0.y -= c0.y; f0.z -= c0.z; f0.w -= c0.w;
        f1.x -= c1.x; f1.y -= c1.y; f1.z -= c1.z; f1.w -= c1.w;
      }
      bf16x8 b;
      b[0]=(short)f2b(f0.x); b[1]=(short)f2b(f0.y); b[2]=(short)f2b(f0.z); b[3]=(short)f2b(f0.w);
      b[4]=(short)f2b(f1.x); b[5]=(short)f2b(f1.y); b[6]=(short)f2b(f1.z); b[7]=(short)f2b(f1.w);
      *reinterpret_cast<bf16x8*>(&Bs[row*256 + (((d >> 3) ^ (row & 7)) << 3)]) = b;
    }
  }

  f32x4 acc[2][4];
#pragma unroll
  for (int mi = 0; mi < 2; ++mi)
#pragma unroll
    for (int ni = 0; ni < 4; ++ni) acc[mi][ni] = (f32x4){0.f,0.f,0.f,0.f};

  float ts[2][4] = {{FLT_MAX,FLT_MAX,FLT_MAX,FLT_MAX},{FLT_MAX,FLT_MAX,FLT_MAX,FLT_MAX}};
  int   ti[2][4] = {{INT_MAX,INT_MAX,INT_MAX,INT_MAX},{INT_MAX,INT_MAX,INT_MAX,INT_MAX}};

  int buf = 0;
  for (int i = 0; i < 32; ++i){
    const int ct = i >> 3, kt = i & 7;
    __syncthreads();
    {
      const int i0 = tid, r0 = i0 >> 2, c0 = i0 & 3;
      *reinterpret_cast<bf16x8*>(&As[buf*8192 + r0*32 + (c0 << 3)]) = s0;
      const int i1 = 512 + tid, r1 = i1 >> 2, c1 = i1 & 3;
      *reinterpret_cast<bf16x8*>(&As[buf*8192 + r1*32 + (c1 << 3)]) = s1;
    }
    if (i < 31){
      const int ni2 = i + 1, nct = ni2 >> 3, nkt = ni2 & 7;
#pragma unroll
      for (int it = 0; it < 2; ++it){
        const int ii = it*512 + tid, r = ii >> 2, c = ii & 3;
        const bf16x8 v = *reinterpret_cast<const bf16x8*>(
            cbb_l + (size_t)(nct*256 + r) * DIM + nkt*32 + ((c ^ (r & 3)) << 3));
        if (it == 0) s0 = v; else s1 = v;
      }
    }
    __syncthreads();

    bf16x8 Bf[2], Af[4];
#pragma unroll
    for (int mi = 0; mi < 2; ++mi){
      const int row = wr*32 + mi*16 + r16;
      Bf[mi] = *reinterpret_cast<const bf16x8*>(
          &Bs[row*256 + (((kt*4 + quad) ^ (row & 7)) << 3)]);
    }
#pragma unroll
    for (int ni = 0; ni < 4; ++ni){
      const int arow = wc*64 + ni*16 + r16;
      Af[ni] = *reinterpret_cast<const bf16x8*>(
          &As[buf*8192 + arow*32 + ((quad ^ (arow & 3)) << 3)]);
    }
#pragma unroll
    for (int ni = 0; ni < 4; ++ni){
      acc[0][ni] = __builtin_amdgcn_mfma_f32_16x16x32_bf16(Af[ni], Bf[0], acc[0][ni], 0, 0, 0);
      acc[1][ni] = __builtin_amdgcn_mfma_f32_16x16x32_bf16(Af[ni], Bf[1], acc[1][ni], 0, 0, 0);
    }

    if (kt == 7){
#pragma unroll
      for (int mi = 0; mi < 2; ++mi)
#pragma unroll
        for (int ni = 0; ni < 4; ++ni){
          const int c0 = ct*256 + wc*64 + ni*16 + quad*4;
          const float4 cn = *reinterpret_cast<const float4*>(cnx_l + c0);
          const f32x4 a = acc[mi][ni];
          ins4(ts[mi], ti[mi], cn.x - 2.f*a[0], c0+0);
          ins4(ts[mi], ti[mi], cn.y - 2.f*a[1], c0+1);
          ins4(ts[mi], ti[mi], cn.z - 2.f*a[2], c0+2);
          ins4(ts[mi], ti[mi], cn.w - 2.f*a[3], c0+3);
          acc[mi][ni] = (f32x4){0.f,0.f,0.f,0.f};
        }
    }
    buf ^= 1;
  }

  __syncthreads();   // As dead from here (aliased)

  // ---- rowmin publish + list init --------------------------------------
#pragma unroll
  for (int mi = 0; mi < 2; ++mi){
    float m = ts[mi][0];
    m = fminf(m, __shfl_xor(m, 16));
    m = fminf(m, __shfl_xor(m, 32));
    if (quad == 0) rowm[(wr*32 + mi*16 + r16)*4 + wc] = m;
  }
  if (tid < 64){ cnt_l[tid] = 0; ovf_l[tid] = 0; }
  __syncthreads();

  // ---- per-lane margin emission (lane-overflow -> hard) -----------------
#pragma unroll
  for (int mi = 0; mi < 2; ++mi){
    const int row = wr*32 + mi*16 + r16;
    const float m1 = fminf(fminf(rowm[row*4], rowm[row*4+1]),
                           fminf(rowm[row*4+2], rowm[row*4+3]));
    const float thr = m1 + AMB;
#pragma unroll
    for (int e = 0; e < 4; ++e){
      if (ts[mi][e] <= thr){
        const int pos = atomicAdd(&cnt_l[row], 1);
        if (pos < 16) cand_l[row*16 + pos] = ti[mi][e];
      }
    }
    if (ts[mi][3] <= thr) ovf_l[row] = 1;   // lane may have dropped entries
  }
  __syncthreads();

  // ---- classify & emit --------------------------------------------------
  int apos = -1, hpos = -1, myc = 0;
  if (tid < 64){
    myc = cnt_l[tid];
    if (!ovf_l[tid] && myc == 1){
      idxw[LVL * NROWS + rowbase + tid] = cand_l[tid*16];
    } else if (!ovf_l[tid] && myc <= 16){
      apos = atomicAdd(&acnt_s, 1);
    } else {
      hpos = atomicAdd(&hcnt_s, 1);
    }
  }
  __syncthreads();
  if (tid == 0){
    abase_s = acnt_s ? atomicAdd(&cnt8[LVL], acnt_s) : 0;
    hbase_s = hcnt_s ? atomicAdd(&cnt8[4 + LVL], hcnt_s) : 0;
  }
  __syncthreads();
  if (apos >= 0){
    int* rp = arecs + (size_t)(abase_s + apos) * REC;
    rp[0] = rowbase + tid; rp[1] = myc;
    for (int e = 0; e < myc; ++e) rp[2+e] = cand_l[tid*16 + e];
  }
  if (hpos >= 0) hrows[hbase_s + hpos] = rowbase + tid;
}

// ---------------- K2a: amb rows — explicit candidates, GUARD, fallback --
// 16 lanes/row; per candidate one coalesced 16-lane dot; parallel top-2
// gap > GUARD decides; else serial-exact (r4-validated chain) on all c.
template<int LVL>
__global__ __launch_bounds__(256)
void rvq_amb(const float* __restrict__ feat,
             const float* __restrict__ cb32,
             const float* __restrict__ cnx_l,
             int* __restrict__ idxw,
             const int* __restrict__ cnt8,
             const int* __restrict__ arecs)
{
  __shared__ float rres[16][260];
  const int tid = threadIdx.x;
  const int g = tid >> 4, q = tid & 15;
  const int cnt = cnt8[LVL];
  const float* cbl = cb32 + (size_t)LVL * KC * DIM;

  for (int rr = blockIdx.x * 16 + g; rr < cnt; rr += gridDim.x * 16){
    const int* rp = arecs + (size_t)rr * REC;
    const int grow = rp[0];
    const int c = rp[1];

    // exact fp32-chain residual (validated) -> regs + LDS stash
    float4 rv[4];
#pragma unroll
    for (int i4 = 0; i4 < 4; ++i4){
      const int d = q*16 + i4*4;
      float4 w = *reinterpret_cast<const float4*>(feat + (size_t)grow * DIM + d);
#pragma unroll
      for (int j2 = 0; j2 < LVL; ++j2){
        const int kj = idxw[(size_t)j2 * NROWS + grow];
        const float4 cv = *reinterpret_cast<const float4*>(
            cb32 + ((size_t)j2 * KC + kj) * DIM + d);
        w.x -= cv.x; w.y -= cv.y; w.z -= cv.z; w.w -= cv.w;
      }
      rv[i4] = w;
      *reinterpret_cast<float4*>(&rres[g][d]) = w;
    }

    // parallel scores, tie-aware top-2
    float m1 = FLT_MAX, m2 = FLT_MAX; int i1 = INT_MAX;
    for (int qq = 0; qq < c; ++qq){
      const int ci = rp[2+qq];
      const float* cp = cbl + (size_t)ci * DIM + q*16;
      float pa = 0.f;
#pragma unroll
      for (int j = 0; j < 4; ++j){
        const float4 cv = *reinterpret_cast<const float4*>(cp + j*4);
        pa = fmaf(rv[j].x, cv.x, pa); pa = fmaf(rv[j].y, cv.y, pa);
        pa = fmaf(rv[j].z, cv.z, pa); pa = fmaf(rv[j].w, cv.w, pa);
      }
#pragma unroll
      for (int m = 1; m < 16; m <<= 1) pa += __shfl_xor(pa, m);
      const float sc = cnx_l[ci] - 2.0f * pa;
      if (sless(sc, ci, m1, i1)){ m2 = m1; m1 = sc; i1 = ci; }
      else m2 = fminf(m2, sc);
    }

    int winner = i1;
    if (!(m2 - m1 > GUARD)){
      // serial-exact (validated chain) on all c candidates, lane-strided
      float bs = FLT_MAX; int bi = INT_MAX;
      for (int k = q; k < c; k += 16){
        const int ci = rp[2+k];
        float a = 0.f;
        for (int d4 = 0; d4 < 64; ++d4){
          const float4 cv = *reinterpret_cast<const float4*>(cbl + (size_t)ci * DIM + d4*4);
          const float4 rw = *reinterpret_cast<const float4*>(&rres[g][d4*4]);
          a = fmaf(rw.x, cv.x, a); a = fmaf(rw.y, cv.y, a);
          a = fmaf(rw.z, cv.z, a); a = fmaf(rw.w, cv.w, a);
        }
        const float sc = cnx_l[ci] - 2.0f * a;
        if (sless(sc, ci, bs, bi)){ bs = sc; bi = ci; }
      }
#pragma unroll
      for (int m = 1; m < 16; m <<= 1){
        const float ob = __shfl_xor(bs, m); const int oi = __shfl_xor(bi, m);
        if (sless(ob, oi, bs, bi)){ bs = ob; bi = oi; }
      }
      winner = bi;
    }
    if (q == 0) idxw[(size_t)LVL * NROWS + grow] = winner;
  }
}

// ---------------- K2b: hard rows — block/row, full 1024 + GUARD ---------
// verbatim r11 (validated); now handles ~0.01% of rows.
template<int LVL>
__global__ __launch_bounds__(256)
void rvq_hard(const float* __restrict__ feat,
              const float* __restrict__ cb32,
              const float* __restrict__ cnx_l,
              int* __restrict__ idxw,
              const int* __restrict__ cnt8,
              const int* __restrict__ hrows)
{
  __shared__ float rres[260];
  __shared__ float scb[1024];
  __shared__ float wmn[4];
  __shared__ float wbs[4];
  __shared__ int   wbi[4];
  const int tid = threadIdx.x;
  const int g = tid >> 4, q = tid & 15;
  const int wv = tid >> 6, ln = tid & 63;
  const int cnt = cnt8[4 + LVL];
  const float* cbl = cb32 + (size_t)LVL * KC * DIM;

  for (int r = blockIdx.x; r < cnt; r += gridDim.x){
    const int grow = hrows[r];
    if (tid < 16){
#pragma unroll
      for (int i4 = 0; i4 < 4; ++i4){
        const int d = tid*16 + i4*4;
        float4 w = *reinterpret_cast<const float4*>(feat + (size_t)grow * DIM + d);
#pragma unroll
        for (int j2 = 0; j2 < LVL; ++j2){
          const int kj = idxw[(size_t)j2 * NROWS + grow];
          const float4 cv = *reinterpret_cast<const float4*>(
              cb32 + ((size_t)j2 * KC + kj) * DIM + d);
          w.x -= cv.x; w.y -= cv.y; w.z -= cv.z; w.w -= cv.w;
        }
        *reinterpret_cast<float4*>(&rres[d]) = w;
      }
    }
    __syncthreads();

    float4 rv[4];
#pragma unroll
    for (int j = 0; j < 4; ++j)
      rv[j] = *reinterpret_cast<const float4*>(&rres[q*16 + j*4]);

    for (int t = 0; t < 64; ++t){
      const int ci = g*64 + t;
      float pa = 0.f;
#pragma unroll
      for (int j = 0; j < 4; ++j){
        const float4 cv = *reinterpret_cast<const float4*>(
            cbl + (size_t)ci * DIM + q*16 + j*4);
        pa = fmaf(rv[j].x, cv.x, pa); pa = fmaf(rv[j].y, cv.y, pa);
        pa = fmaf(rv[j].z, cv.z, pa); pa = fmaf(rv[j].w, cv.w, pa);
      }
#pragma unroll
      for (int m = 1; m < 16; m <<= 1) pa += __shfl_xor(pa, m);
      if (q == 0) scb[ci] = cnx_l[ci] - 2.0f * pa;
    }
    __syncthreads();

    float mn = fminf(fminf(scb[tid], scb[tid+256]), fminf(scb[tid+512], scb[tid+768]));
#pragma unroll
    for (int m = 1; m < 64; m <<= 1) mn = fminf(mn, __shfl_xor(mn, m));
    if (ln == 0) wmn[wv] = mn;
    __syncthreads();
    const float m1p = fminf(fminf(wmn[0], wmn[1]), fminf(wmn[2], wmn[3]));
    const float thr = m1p + GUARD;

    float bs = FLT_MAX; int bi = INT_MAX;
#pragma unroll
    for (int k = 0; k < 4; ++k){
      const int ci = tid + k*256;
      if (scb[ci] <= thr){
        float a = 0.f;
        for (int d4 = 0; d4 < 64; ++d4){
          const float4 cv = *reinterpret_cast<const float4*>(cbl + (size_t)ci * DIM + d4*4);
          const float4 rw = *reinterpret_cast<const float4*>(&rres[d4*4]);
          a = fmaf(rw.x, cv.x, a); a = fmaf(rw.y, cv.y, a);
          a = fmaf(rw.z, cv.z, a); a = fmaf(rw.w, cv.w, a);
        }
        const float sc = cnx_l[ci] - 2.0f * a;
        if (sless(sc, ci, bs, bi)){ bs = sc; bi = ci; }
      }
    }
#pragma unroll
    for (int m = 1; m < 64; m <<= 1){
      const float ob = __shfl_xor(bs, m); const int oi = __shfl_xor(bi, m);
      if (sless(ob, oi, bs, bi)){ bs = ob; bi = oi; }
    }
    if (ln == 0){ wbs[wv] = bs; wbi[wv] = bi; }
    __syncthreads();
    if (tid == 0){
      float fb = wbs[0]; int fi = wbi[0];
#pragma unroll
      for (int w = 1; w < 4; ++w)
        if (sless(wbs[w], wbi[w], fb, fi)){ fb = wbs[w]; fi = wbi[w]; }
      idxw[(size_t)LVL * NROWS + grow] = fi;
    }
    __syncthreads();
  }
}

// ---------------- K3: final output = q0+q1+q2+q3 (validated r5-r11) -----
__global__ __launch_bounds__(256)
void rvq_out(const float* __restrict__ cb32,
             const int* __restrict__ idxw,
             float* __restrict__ out)
{
  const int tid = threadIdx.x;
  const int row = tid >> 4, sub = tid & 15;
  const size_t n = (size_t)blockIdx.x * 16 + row;
  int hist[NLVL];
#pragma unroll
  for (int j2 = 0; j2 < 4; ++j2) hist[j2] = idxw[(size_t)j2 * NROWS + n];
#pragma unroll
  for (int i = 0; i < 4; ++i){
    const int d = sub*4 + i*64;
    float4 a = *reinterpret_cast<const float4*>(
        cb32 + ((size_t)0 * KC + hist[0]) * DIM + d);
#pragma unroll
    for (int j2 = 1; j2 < 4; ++j2){
      const float4 qv = *reinterpret_cast<const float4*>(
          cb32 + ((size_t)j2 * KC + hist[j2]) * DIM + d);
      a.x += qv.x; a.y += qv.y; a.z += qv.z; a.w += qv.w;
    }
    *reinterpret_cast<float4*>(out + n*DIM + d) = a;
  }
}

extern "C" void kernel_launch(void* const* d_in, const int* in_sizes, int n_in,
                              void* d_out, int out_size, void* d_ws, size_t ws_size,
                              hipStream_t stream){
  const float* feat = (const float*)d_in[0];
  const float* cb32 = (const float*)d_in[1];
  float* out = (float*)d_out;

  char* ws = (char*)d_ws;
  float* cnx  = (float*)(ws);                              // 16 KB
  int*   cnt8 = (int*)(ws + 16384);                        // 8 counters
  unsigned short* cbb = (unsigned short*)(ws + 32768);     // 2 MB
  int*   idxw = (int*)(ws + 32768 + 2097152);              // 2 MB
  int*   arecs = (int*)(ws + 32768 + 2097152 + 2097152);   // 9.5 MB
  int*   hrows = (int*)(ws + 32768 + 2097152 + 2097152 + 9961472); // 512 KB

  zero8<<<1, 64, 0, stream>>>(cnt8);
  prep_cbb<<<1024, 256, 0, stream>>>(cb32, cbb);
  prep_cn<<<64, 64, 0, stream>>>(cb32, cnx);

#define LVL_STEP(L) \
  rvq_score<L><<<2048, 512, 0, stream>>>(feat, cb32, cbb + (size_t)L*KC*DIM, \
      cnx + L*KC, idxw, cnt8, arecs, hrows); \
  rvq_amb<L><<<2048, 256, 0, stream>>>(feat, cb32, cnx + L*KC, idxw, cnt8, arecs); \
  rvq_hard<L><<<512, 256, 0, stream>>>(feat, cb32, cnx + L*KC, idxw, cnt8, hrows);

  LVL_STEP(0)
  LVL_STEP(1)
  LVL_STEP(2)
  LVL_STEP(3)
#undef LVL_STEP

  rvq_out<<<8192, 256, 0, stream>>>(cb32, idxw, out);
}